// Round 5
// baseline (468.007 us; speedup 1.0000x reference)
//
#include <hip/hip_runtime.h>

typedef float f32x2 __attribute__((ext_vector_type(2)));

#define IMG_W 512
#define IMG_H 512
#define TY 4
#define TX 256
#define PLANES 96              // N*C = 32*3
#define NPIX (32ll * 3 * 512 * 512)

// Separable Gaussian, sigma=1.5, size=11, normalized (compile-time folded).
#define WG_INIT { 0.00102838f, 0.00759876f, 0.03600077f, 0.10936069f, \
                  0.21300553f, 0.26601172f, 0.21300553f, 0.10936069f, \
                  0.03600077f, 0.00759876f, 0.00102838f }

// LDS layout: 5 maps x 2 row-pair slabs x 136 atoms of 16 B.
// Atom a holds entries 2a,2a+1; entry e = f32x2{row 2rp, row 2rp+1} at col e.
// XOR swizzle a' = a ^ ((a>>3)&7): makes the horizontal read pattern
// (lane g -> atoms 2g+q) hit all 8 bank-slots per 8 lanes (conflict-free)
// and the write pattern 2-way (free per m136).
#define SLAB_BYTES (136 * 16)         // 2176 B per (map,rp)
#define MAP_BYTES  (2 * SLAB_BYTES)   // 4352 B per map

__global__ __launch_bounds__(256)
void ssim_main(const float* __restrict__ pred, const float* __restrict__ targ,
               double* __restrict__ acc) {
    const float WG[11] = WG_INIT;

    __shared__ __align__(16) unsigned char ldsraw[5 * MAP_BYTES];  // 21760 B
    __shared__ float wsum[4];

    const int tid   = threadIdx.x;
    const int plane = blockIdx.z;
    const int y0    = blockIdx.y * TY;
    const int xbase = blockIdx.x * TX - 5;   // image col of LDS entry 0
    const size_t base = (size_t)plane * (IMG_W * IMG_H);

    // ---- vertical pass for one entry-column c (image col xbase+c) ----
    auto do_col = [&](int c) {
        const int  cx  = xbase + c;
        const bool okx = (unsigned)cx < (unsigned)IMG_W;
        const size_t cbase = base + (size_t)(okx ? cx : 0);

        float pv[TY + 10], tv[TY + 10];
#pragma unroll
        for (int iy = 0; iy < TY + 10; ++iy) {
            const int  y  = y0 - 5 + iy;
            const bool ok = okx && ((unsigned)y < (unsigned)IMG_H);
            pv[iy] = ok ? pred[cbase + (size_t)y * IMG_W] : 0.f;
            tv[iy] = ok ? targ[cbase + (size_t)y * IMG_W] : 0.f;
        }

        f32x2 A[5][2];
#pragma unroll
        for (int m = 0; m < 5; ++m) { A[m][0] = (f32x2){0.f,0.f}; A[m][1] = (f32x2){0.f,0.f}; }

#pragma unroll
        for (int iy = 0; iy < TY + 10; ++iy) {
            const float p = pv[iy], t = tv[iy];
            const float pp = p * p, tt = t * t, pt = p * t;
            const f32x2 vs[5] = { {p,p}, {t,t}, {pp,pp}, {tt,tt}, {pt,pt} };
#pragma unroll
            for (int rp = 0; rp < 2; ++rp) {
                const int a = iy - 2 * rp;                      // compile-time
                if (a < 0 || a > 11) continue;                  // both lanes zero
                const float w0 = (a <= 10) ? WG[a] : 0.f;       // row 2rp
                const float w1 = (a >= 1)  ? WG[a - 1] : 0.f;   // row 2rp+1
                const f32x2 w = (f32x2){w0, w1};
#pragma unroll
                for (int m = 0; m < 5; ++m)
                    A[m][rp] = __builtin_elementwise_fma(vs[m], w, A[m][rp]);
            }
        }

        const int at  = c >> 1;
        const int ap  = at ^ ((at >> 3) & 7);
        const int bof = ap * 16 + (c & 1) * 8;
#pragma unroll
        for (int m = 0; m < 5; ++m) {
            *(f32x2*)(ldsraw + m * MAP_BYTES + 0 * SLAB_BYTES + bof) = A[m][0];
            *(f32x2*)(ldsraw + m * MAP_BYTES + 1 * SLAB_BYTES + bof) = A[m][1];
        }
    };

    do_col(tid);                 // entry cols 0..255
    if (tid < 10) do_col(TX + tid);   // halo entry cols 256..265 (regs reused)
    __syncthreads();

    // ---- horizontal pass + SSIM: 128 threads x 4 cols x 1 row-pair = 8 px ----
    const float C1 = 1e-4f, C2 = 9e-4f;
    float lsum = 0.f;

    if (tid < 128) {
        const int rp = tid >> 6;        // wave 0 -> rp0, wave 1 -> rp1
        const int g  = tid & 63;        // col group: out cols 4g..4g+3
        const unsigned char* slab = ldsraw + rp * SLAB_BYTES;

        f32x2 H[5][4];
#pragma unroll
        for (int m = 0; m < 5; ++m) {
            f32x2 win[14];   // entries 4g .. 4g+13
#pragma unroll
            for (int q = 0; q < 7; ++q) {
                const int at = 2 * g + q;            // swizzle CSE'd across m
                const int ap = at ^ ((at >> 3) & 7);
                const float4 v = *(const float4*)(slab + m * MAP_BYTES + ap * 16);
                win[2*q]   = (f32x2){v.x, v.y};
                win[2*q+1] = (f32x2){v.z, v.w};
            }
#pragma unroll
            for (int d = 0; d < 4; ++d) {
                f32x2 h = (f32x2){0.f, 0.f};
#pragma unroll
                for (int k = 0; k < 11; ++k) {
                    const f32x2 wk = (f32x2){WG[k], WG[k]};
                    h = __builtin_elementwise_fma(win[d + k], wk, h);
                }
                H[m][d] = h;
            }
        }

#pragma unroll
        for (int d = 0; d < 4; ++d) {
            f32x2 mu1 = H[0][d], mu2 = H[1][d];
            f32x2 mu1s = mu1 * mu1, mu2s = mu2 * mu2, mu12 = mu1 * mu2;
            f32x2 s1  = H[2][d] - mu1s;
            f32x2 s2  = H[3][d] - mu2s;
            f32x2 s12 = H[4][d] - mu12;
            f32x2 num = (mu12 + mu12 + (f32x2){C1, C1}) *
                        (s12 + s12 + (f32x2){C2, C2});
            f32x2 den = (mu1s + mu2s + (f32x2){C1, C1}) *
                        (s1 + s2 + (f32x2){C2, C2}) + (f32x2){1e-8f, 1e-8f};
            lsum += num.x * __builtin_amdgcn_rcpf(den.x);
            lsum += num.y * __builtin_amdgcn_rcpf(den.y);
        }
    }

    // ---- reduction: wave shuffle -> LDS -> one double atomic per block ----
#pragma unroll
    for (int off = 32; off > 0; off >>= 1)
        lsum += __shfl_down(lsum, off);
    if ((tid & 63) == 0) wsum[tid >> 6] = lsum;
    __syncthreads();
    if (tid == 0) {
        float s = wsum[0] + wsum[1] + wsum[2] + wsum[3];
        atomicAdd(acc, (double)s);
    }
}

__global__ void ssim_final(const double* __restrict__ acc, float* __restrict__ out) {
    out[0] = 1.0f - (float)(acc[0] * (1.0 / (double)NPIX));
}

extern "C" void kernel_launch(void* const* d_in, const int* in_sizes, int n_in,
                              void* d_out, int out_size, void* d_ws, size_t ws_size,
                              hipStream_t stream) {
    const float* pred = (const float*)d_in[0];
    const float* targ = (const float*)d_in[1];
    double* acc = (double*)d_ws;

    hipMemsetAsync(acc, 0, sizeof(double), stream);

    dim3 grid(IMG_W / TX, IMG_H / TY, PLANES);   // (2, 128, 96)
    ssim_main<<<grid, 256, 0, stream>>>(pred, targ, acc);
    ssim_final<<<1, 1, 0, stream>>>(acc, (float*)d_out);
}

// Round 6
// 245.939 us; speedup vs baseline: 1.9029x; 1.9029x over previous
//
#include <hip/hip_runtime.h>

typedef float f32x2 __attribute__((ext_vector_type(2)));

#define IMG_W 512
#define IMG_H 512
#define TY 8
#define PLANES 96              // N*C = 32*3
#define NPIX (32ll * 3 * 512 * 512)
#define NACC 64                // atomic fanout slots

// Separable Gaussian, sigma=1.5, size=11, normalized (compile-time folded).
#define WG_INIT { 0.00102838f, 0.00759876f, 0.03600077f, 0.10936069f, \
                  0.21300553f, 0.26601172f, 0.21300553f, 0.10936069f, \
                  0.03600077f, 0.00759876f, 0.00102838f }

// LDS: 10 slabs (5 maps x 2 row-pair) x 264 atoms x 16 B = 42240 B.
// Entry e (e=0..527) = f32x2{row 2rp, row 2rp+1} at padded col e (data col e-8).
// Atom at = e>>1 holds entries 2at,2at+1. XOR swizzle ap = at ^ ((at>>3)&7):
// horizontal reads (lane g -> atoms g+1..g+7) conflict-free, writes 2-way (free).
#define SLAB_ATOMS 264
#define SLAB_BYTES (SLAB_ATOMS * 16)

__device__ __forceinline__ int swz(int at) { return at ^ ((at >> 3) & 7); }

__global__ __launch_bounds__(512)   // NO min-waves arg: (512,4) forced a 64-VGPR
                                    // cap and 393 MB of spill in R2 (measured)
void ssim_main(const float* __restrict__ pred, const float* __restrict__ targ,
               double* __restrict__ acc) {
    const float WG[11] = WG_INIT;

    __shared__ __align__(16) unsigned char ldsraw[10 * SLAB_BYTES];
    __shared__ float wsum[8];

    const int tid   = threadIdx.x;
    const int x     = tid;                 // column owned in vertical pass
    const int plane = blockIdx.y;
    const int y0    = blockIdx.x * TY;
    const size_t base = (size_t)plane * (IMG_W * IMG_H);
    const float* pCol = pred + base + x;
    const float* tCol = targ + base + x;

    // Zero horizontal halo pads: atoms 0..3 and 260..263 in each of 10 slabs.
    // Data writes never touch them; they stay zero across both halves.
    if (tid < 80) {
        const int s   = tid >> 3;               // slab 0..9
        const int idx = tid & 7;                // 0..7
        const int at  = (idx < 4) ? idx : (256 + idx);   // 0..3 / 260..263
        *(float4*)(ldsraw + s * SLAB_BYTES + swz(at) * 16) =
            (float4){0.f, 0.f, 0.f, 0.f};
    }

    // ---- vertical pass: 18 rows -> 8 output rows as 4 packed row-pairs ----
    float pv[TY + 10], tv[TY + 10];
#pragma unroll
    for (int iy = 0; iy < TY + 10; ++iy) {
        const int y = y0 - 5 + iy;
        pv[iy] = 0.f; tv[iy] = 0.f;
        if ((unsigned)y < (unsigned)IMG_H) {    // wave-uniform
            pv[iy] = pCol[(size_t)y * IMG_W];
            tv[iy] = tCol[(size_t)y * IMG_W];
        }
    }

    f32x2 A[5][4];
#pragma unroll
    for (int m = 0; m < 5; ++m)
#pragma unroll
        for (int rp = 0; rp < 4; ++rp) A[m][rp] = (f32x2){0.f, 0.f};

#pragma unroll
    for (int iy = 0; iy < TY + 10; ++iy) {
        const float p = pv[iy], t = tv[iy];
        const float pp = p * p, tt = t * t, pt = p * t;
        const f32x2 vs[5] = { {p,p}, {t,t}, {pp,pp}, {tt,tt}, {pt,pt} };
#pragma unroll
        for (int rp = 0; rp < 4; ++rp) {
            const int a = iy - 2 * rp;                      // compile-time
            if (a < 0 || a > 11) continue;                  // both lanes zero
            const float w0 = (a <= 10) ? WG[a] : 0.f;       // row 2rp
            const float w1 = (a >= 1)  ? WG[a - 1] : 0.f;   // row 2rp+1
            const f32x2 w = (f32x2){w0, w1};
#pragma unroll
            for (int m = 0; m < 5; ++m)
                A[m][rp] = __builtin_elementwise_fma(vs[m], w, A[m][rp]);
        }
    }

    // ---- horizontal pass + SSIM, two 4-row halves through LDS ----
    const float C1 = 1e-4f, C2 = 9e-4f;
    float lsum = 0.f;
    const int rpl = tid >> 8;          // 0..1: slab this thread reads
    const int g   = tid & 255;         // col group: packed out-cols 2g, 2g+1
    // write address: entry c = x+8
    const int wat = (x + 8) >> 1;
    const int wof = swz(wat) * 16 + ((x + 8) & 1) * 8;

#pragma unroll
    for (int half = 0; half < 2; ++half) {
        __syncthreads();   // pads ready (1st) / previous half consumed (2nd)
#pragma unroll
        for (int m = 0; m < 5; ++m)
#pragma unroll
            for (int rl = 0; rl < 2; ++rl)
                *(f32x2*)(ldsraw + (m * 2 + rl) * SLAB_BYTES + wof) =
                    A[m][2 * half + rl];
        __syncthreads();

        // out cols 2g,2g+1 need entries 2g+3..2g+14 -> atoms g+1..g+7.
        f32x2 H[5][2];
#pragma unroll
        for (int m = 0; m < 5; ++m) {
            const unsigned char* slab = ldsraw + (m * 2 + rpl) * SLAB_BYTES;
            f32x2 win[14];
#pragma unroll
            for (int q = 0; q < 7; ++q) {
                const float4 v = *(const float4*)(slab + swz(g + 1 + q) * 16);
                win[2*q]   = (f32x2){v.x, v.y};
                win[2*q+1] = (f32x2){v.z, v.w};
            }
            f32x2 h0 = (f32x2){0.f, 0.f}, h1 = (f32x2){0.f, 0.f};
#pragma unroll
            for (int k = 0; k < 11; ++k) {
                const f32x2 wk = (f32x2){WG[k], WG[k]};
                h0 = __builtin_elementwise_fma(win[1 + k], wk, h0);
                h1 = __builtin_elementwise_fma(win[2 + k], wk, h1);
            }
            H[m][0] = h0; H[m][1] = h1;
        }

#pragma unroll
        for (int c = 0; c < 2; ++c) {
            f32x2 mu1 = H[0][c], mu2 = H[1][c];
            f32x2 mu1s = mu1 * mu1, mu2s = mu2 * mu2, mu12 = mu1 * mu2;
            f32x2 s1  = H[2][c] - mu1s;
            f32x2 s2  = H[3][c] - mu2s;
            f32x2 s12 = H[4][c] - mu12;
            f32x2 num = (mu12 + mu12 + (f32x2){C1, C1}) *
                        (s12 + s12 + (f32x2){C2, C2});
            f32x2 den = (mu1s + mu2s + (f32x2){C1, C1}) *
                        (s1 + s2 + (f32x2){C2, C2}) + (f32x2){1e-8f, 1e-8f};
            lsum += num.x * __builtin_amdgcn_rcpf(den.x);
            lsum += num.y * __builtin_amdgcn_rcpf(den.y);
        }
    }

    // ---- reduction: wave shuffle -> LDS -> one atomic per block (64 slots) ----
#pragma unroll
    for (int off = 32; off > 0; off >>= 1)
        lsum += __shfl_down(lsum, off);
    if ((tid & 63) == 0) wsum[tid >> 6] = lsum;
    __syncthreads();
    if (tid == 0) {
        float s = 0.f;
#pragma unroll
        for (int i = 0; i < 8; ++i) s += wsum[i];
        atomicAdd(&acc[blockIdx.x & (NACC - 1)], (double)s);
    }
}

__global__ void ssim_final(const double* __restrict__ acc, float* __restrict__ out) {
    double s = 0.0;
#pragma unroll
    for (int i = 0; i < NACC; ++i) s += acc[i];
    out[0] = 1.0f - (float)(s * (1.0 / (double)NPIX));
}

extern "C" void kernel_launch(void* const* d_in, const int* in_sizes, int n_in,
                              void* d_out, int out_size, void* d_ws, size_t ws_size,
                              hipStream_t stream) {
    const float* pred = (const float*)d_in[0];
    const float* targ = (const float*)d_in[1];
    double* acc = (double*)d_ws;

    hipMemsetAsync(acc, 0, NACC * sizeof(double), stream);

    dim3 grid(IMG_H / TY, PLANES);   // adjacent strips -> halo L2 reuse (R1: 219 MB)
    ssim_main<<<grid, 512, 0, stream>>>(pred, targ, acc);
    ssim_final<<<1, 1, 0, stream>>>(acc, (float*)d_out);
}